// Round 15
// baseline (423.025 us; speedup 1.0000x reference)
//
#include <hip/hip_runtime.h>

#define BATCH 256
#define SEQ   2048
#define NC    32
#define EMB   2048
#define NT    32          // SEQ / BK, BK = 64

typedef unsigned short ushort_t;
using f32x4  = __attribute__((ext_vector_type(4))) float;
using bf16x8 = __attribute__((ext_vector_type(8))) short;

using u32_gl = __attribute__((address_space(1))) const unsigned int;
using u32_ld = __attribute__((address_space(3))) unsigned int;

__device__ __forceinline__ unsigned int f2bf(float f) {
  unsigned int u = __float_as_uint(f);
  u += 0x7FFFu + ((u >> 16) & 1u);   // RNE (finite inputs)
  return u >> 16;
}

#define SB() __builtin_amdgcn_sched_barrier(0)

// ---------------------------------------------------------------------------
// x: (B, S, C) f32  ->  xT: (C, B, S) bf16
// ---------------------------------------------------------------------------
__global__ __launch_bounds__(256) void transpose_x_kernel(
    const float* __restrict__ x, ushort_t* __restrict__ xT) {
  __shared__ float tile[64][33];
  const int b  = blockIdx.x >> 5;
  const int st = blockIdx.x & 31;
  const int t  = threadIdx.x;
  const float* src = x + ((size_t)b * SEQ + (size_t)st * 64) * NC;
#pragma unroll
  for (int i = 0; i < 2; ++i) {
    int idx = t + i * 256;
    float4 v = reinterpret_cast<const float4*>(src)[idx];
    int s = idx >> 3;
    int c = (idx & 7) * 4;
    tile[s][c + 0] = v.x; tile[s][c + 1] = v.y;
    tile[s][c + 2] = v.z; tile[s][c + 3] = v.w;
  }
  __syncthreads();
  const int c  = t >> 3;
  const int si = (t & 7) * 8;
  unsigned int q[4];
#pragma unroll
  for (int p = 0; p < 4; ++p) {
    unsigned int h0 = f2bf(tile[si + 2 * p + 0][c]);
    unsigned int h1 = f2bf(tile[si + 2 * p + 1][c]);
    q[p] = h0 | (h1 << 16);
  }
  ushort_t* dst = xT + (size_t)c * (BATCH * SEQ) + (size_t)b * SEQ + st * 64 + si;
  *reinterpret_cast<uint4*>(dst) = make_uint4(q[0], q[1], q[2], q[3]);
}

// ---------------------------------------------------------------------------
// H-page final test: BM=256 / BN=256 / BK=64, 1024 thr = 16 waves (4m x 4e),
// per-wave 64m x 64e -> acc[4][4] = 64 AGPR (unified-file budget at
// 4 waves/SIMD = 128/wave -> 64 arch VGPR target).
// W regs: TWO banks of 8 (w1: rows srow*4+{0,1}; w2: rows +{2,3}), each
// consumed (convert) then immediately reissued for t+1 -> 16 W regs total.
// W reads: per instr 64 lanes x 4 B = 256 B contiguous; per row 4 instrs
// back-to-back = 1 KB contiguous per block (DRAM page locality).
// Schedule (1-barrier, counted vmcnt; queue invariant [Wp1:8, A:2, Wp2:8]):
//   1. vmcnt(10): Wp1(t) ready     2. convert p1 -> Blds[P] (4B writes)
//   3. issue Wp1(t+1):8            4. vmcnt(8): A(t)+Wp2(t) landed
//   5. convert p2 -> Blds[P]       6. lgkmcnt(0) + s_barrier
//   7. issue gl_lds A(t+1):2       8. issue Wp2(t+1):8
//   9. compute(t): per ks load af[4]; per e-half bfr[2]; 16 MFMA
// LDS: A dbuf 2x32 KB + B dbuf 2x32 KB = 128 KB; 256 blocks, single round.
// ---------------------------------------------------------------------------
template <int P>
__device__ __forceinline__ void gemm_iter(
    int t, const ushort_t* __restrict__ xTc, const float* __restrict__ Wc,
    char* Alds, char* Blds, float (&w1)[8], float (&w2)[8], f32x4 (&acc)[4][4],
    int tid, int wr, int wc, int g, int lm, int e0) {
  const int srow4 = tid >> 6;        // 0..15 -> W s-rows srow4*4..+3
  const int e4    = tid & 63;        // 0..63 -> base e column

  // ---- 1. Wp1(t) ready; leave [A(t):2, Wp2(t):8] ----
  asm volatile("s_waitcnt vmcnt(10)" ::: "memory");

  // ---- 2. convert p1 (rows srow4*4+0,+1) -> 4B writes at byte 2*s0 ----
#pragma unroll
  for (int i = 0; i < 4; ++i) {
    const int e = e4 + 64 * i;
    unsigned int v = f2bf(w1[0 * 4 + i]) | (f2bf(w1[1 * 4 + i]) << 16);
    int byte = (e * 128 + srow4 * 8) ^ ((e & 7) << 4);
    *reinterpret_cast<unsigned int*>(Blds + P * 32768 + byte) = v;
  }
  SB();

  // ---- 3. issue Wp1(t+1): rows +0,+1 (256B/instr, NT) ----
  {
    const int tn = (t + 1) & (NT - 1);
    const float* wp = Wc + (size_t)(tn * 64 + srow4 * 4) * EMB + e0 + e4;
#pragma unroll
    for (int r = 0; r < 2; ++r)
#pragma unroll
      for (int i = 0; i < 4; ++i)
        w1[r * 4 + i] =
            __builtin_nontemporal_load(wp + (size_t)r * EMB + 64 * i);
  }
  SB();

  // ---- 4. A(t) + Wp2(t) landed; leave Wp1(t+1):8 ----
  asm volatile("s_waitcnt vmcnt(8)" ::: "memory");

  // ---- 5. convert p2 (rows +2,+3) -> 4B writes at byte 2*s0+4 ----
#pragma unroll
  for (int i = 0; i < 4; ++i) {
    const int e = e4 + 64 * i;
    unsigned int v = f2bf(w2[0 * 4 + i]) | (f2bf(w2[1 * 4 + i]) << 16);
    int byte = (e * 128 + srow4 * 8 + 4) ^ ((e & 7) << 4);
    *reinterpret_cast<unsigned int*>(Blds + P * 32768 + byte) = v;
  }
  SB();

  // ---- 6. single barrier (B writes + A arrival sealed) ----
  asm volatile("s_waitcnt lgkmcnt(0)" ::: "memory");
  __builtin_amdgcn_s_barrier();

  // ---- 7. stage A(t+1) (2048 chunks, 2/thread) ----
  {
    const int s0n = ((t + 1) & (NT - 1)) * 64;
#pragma unroll
    for (int i = 0; i < 2; ++i) {
      int ch   = i * 1024 + tid;
      int m    = ch >> 3;
      int slot = (ch & 7) ^ (m & 7);
      const ushort_t* src = xTc + (size_t)m * SEQ + s0n + slot * 8;
      __builtin_amdgcn_global_load_lds(
          (u32_gl*)src, (u32_ld*)(Alds + (P ^ 1) * 32768 + ch * 16), 16, 0, 0);
    }
  }
  SB();

  // ---- 8. issue Wp2(t+1): rows +2,+3 ----
  {
    const int tn = (t + 1) & (NT - 1);
    const float* wp = Wc + (size_t)(tn * 64 + srow4 * 4 + 2) * EMB + e0 + e4;
#pragma unroll
    for (int r = 0; r < 2; ++r)
#pragma unroll
      for (int i = 0; i < 4; ++i)
        w2[r * 4 + i] =
            __builtin_nontemporal_load(wp + (size_t)r * EMB + 64 * i);
  }
  SB();

  // ---- 9. compute(t): af[4] per ks; bfr[2] per e-half ----
#pragma unroll
  for (int ks = 0; ks < 2; ++ks) {
    bf16x8 af[4];
#pragma unroll
    for (int mi = 0; mi < 4; ++mi) {
      int m_local = wr * 64 + mi * 16 + lm;
      int byte = (m_local * 128 + (ks * 4 + g) * 16) ^ ((m_local & 7) << 4);
      af[mi] = *reinterpret_cast<const bf16x8*>(Alds + P * 32768 + byte);
    }
#pragma unroll
    for (int nh = 0; nh < 2; ++nh) {
      bf16x8 bfr[2];
#pragma unroll
      for (int nj = 0; nj < 2; ++nj) {
        int e_local = wc * 64 + (nh * 2 + nj) * 16 + lm;
        int byte = (e_local * 128 + (ks * 4 + g) * 16) ^ ((e_local & 7) << 4);
        bfr[nj] = *reinterpret_cast<const bf16x8*>(Blds + P * 32768 + byte);
      }
#pragma unroll
      for (int mi = 0; mi < 4; ++mi)
#pragma unroll
        for (int nj = 0; nj < 2; ++nj)
          acc[mi][nh * 2 + nj] = __builtin_amdgcn_mfma_f32_16x16x32_bf16(
              af[mi], bfr[nj], acc[mi][nh * 2 + nj], 0, 0, 0);
    }
  }
}

__global__ __launch_bounds__(1024, 1) void grouped_gemm_pipe(
    const ushort_t* __restrict__ xT,  // (C,B,S) bf16
    const float* __restrict__ W,      // (C,S,E) f32
    const float* __restrict__ bias,   // (C,E) f32
    float* __restrict__ out) {        // (B,C,E) f32
  __shared__ ushort_t AldsU[2][256 * 64];  // 64 KB
  __shared__ ushort_t BldsU[2][256 * 64];  // 64 KB -> 128 KB total

  // Bijective XCD-chunked swizzle: nwg = 256, 32 per XCD.
  const int bid = (blockIdx.x & 7) * 32 + (blockIdx.x >> 3);
  const int c   = bid >> 3;          // 0..31
  const int et  = bid & 7;
  const int e0  = et * 256;

  const int tid  = threadIdx.x;
  const int w    = tid >> 6;         // 0..15
  const int wr   = w >> 2;           // 0..3 m-quadrant (64 rows)
  const int wc   = w & 3;            // 0..3 e-quadrant (64 cols)
  const int lane = tid & 63;
  const int g    = lane >> 4;
  const int lm   = lane & 15;

  const float* Wc = W + (size_t)c * SEQ * EMB;
  const ushort_t* xTc = xT + (size_t)c * (BATCH * SEQ);
  char* Alds = (char*)&AldsU[0][0];
  char* Blds = (char*)&BldsU[0][0];

  float w1[8], w2[8];
  f32x4 acc[4][4];
#pragma unroll
  for (int i = 0; i < 4; ++i)
#pragma unroll
    for (int j = 0; j < 4; ++j) acc[i][j] = (f32x4){0.f, 0.f, 0.f, 0.f};

  // ---- prologue: issue Wp1(0):8, A(0):2, Wp2(0):8 -> queue = 18 ----
  {
    const int srow4 = tid >> 6;
    const int e4    = tid & 63;
    const float* wp = Wc + (size_t)(srow4 * 4) * EMB + e0 + e4;
#pragma unroll
    for (int r = 0; r < 2; ++r)
#pragma unroll
      for (int i = 0; i < 4; ++i)
        w1[r * 4 + i] =
            __builtin_nontemporal_load(wp + (size_t)r * EMB + 64 * i);
    SB();
#pragma unroll
    for (int i = 0; i < 2; ++i) {
      int ch   = i * 1024 + tid;
      int m    = ch >> 3;
      int slot = (ch & 7) ^ (m & 7);
      const ushort_t* src = xTc + (size_t)m * SEQ + slot * 8;
      __builtin_amdgcn_global_load_lds(
          (u32_gl*)src, (u32_ld*)(Alds + ch * 16), 16, 0, 0);
    }
    SB();
#pragma unroll
    for (int r = 0; r < 2; ++r)
#pragma unroll
      for (int i = 0; i < 4; ++i)
        w2[r * 4 + i] =
            __builtin_nontemporal_load(wp + (size_t)(r + 2) * EMB + 64 * i);
    SB();
  }

  // ---- main loop, unroll-by-2 for compile-time parity ----
  for (int t = 0; t < NT; t += 2) {
    gemm_iter<0>(t,     xTc, Wc, Alds, Blds, w1, w2, acc, tid, wr, wc, g, lm, e0);
    gemm_iter<1>(t + 1, xTc, Wc, Alds, Blds, w1, w2, acc, tid, wr, wc, g, lm, e0);
  }

  // drain wrapped prefetch before epilogue
  asm volatile("s_waitcnt vmcnt(0)" ::: "memory");

  // ---- epilogue: bias + ReLU; NT stores ----
  const float* bc = bias + (size_t)c * EMB;
#pragma unroll
  for (int ni = 0; ni < 4; ++ni) {
    const int e = e0 + wc * 64 + ni * 16 + lm;
    const float bv = bc[e];
#pragma unroll
    for (int mi = 0; mi < 4; ++mi) {
      f32x4 a = acc[mi][ni];
      const int mbase = wr * 64 + mi * 16 + g * 4;
#pragma unroll
      for (int r = 0; r < 4; ++r) {
        float v = a[r] + bv;
        v = fmaxf(v, 0.f);
        __builtin_nontemporal_store(
            v, out + ((size_t)(mbase + r) * NC + c) * EMB + e);
      }
    }
  }
}

// ---------------------------------------------------------------------------
// Fallback (no workspace): round-1 style, A loaded strided from x directly.
// ---------------------------------------------------------------------------
__global__ __launch_bounds__(256, 2) void grouped_gemm_fallback(
    const float* __restrict__ x, const float* __restrict__ W,
    const float* __restrict__ bias, float* __restrict__ out) {
  __shared__ ushort_t Alds[128 * 64];
  __shared__ ushort_t Blds[128 * 64];
  const int bid = blockIdx.x;
  const int c   = bid >> 5;
  const int et  = (bid >> 1) & 15;
  const int bt  = bid & 1;
  const int b0  = bt * 128;
  const int e0  = et * 128;
  const int tid  = threadIdx.x;
  const int w    = tid >> 6;
  const int wr   = w >> 1;
  const int wc   = w & 1;
  const int lane = tid & 63;
  const int g    = lane >> 4;
  const int lm   = lane & 15;
  const float* Wc = W + (size_t)c * SEQ * EMB;
  const int srow8 = tid >> 5;
  const int e4    = tid & 31;
  f32x4 acc[4][4];
#pragma unroll
  for (int i = 0; i < 4; ++i)
#pragma unroll
    for (int j = 0; j < 4; ++j) acc[i][j] = (f32x4){0.f, 0.f, 0.f, 0.f};
  for (int s0 = 0; s0 < SEQ; s0 += 64) {
#pragma unroll
    for (int i = 0; i < 4; ++i) {
      int ch   = i * 256 + tid;
      int m    = ch >> 3;
      int slot = (ch & 7) ^ (m & 7);
      const float* src = x + (size_t)(b0 + m) * (SEQ * NC)
                           + (size_t)(s0 + slot * 8) * NC + c;
      unsigned int q[4];
#pragma unroll
      for (int p = 0; p < 4; ++p) {
        unsigned int h0 = f2bf(src[(2 * p + 0) * NC]);
        unsigned int h1 = f2bf(src[(2 * p + 1) * NC]);
        q[p] = h0 | (h1 << 16);
      }
      *reinterpret_cast<uint4*>((char*)&Alds[0] + ch * 16) =
          make_uint4(q[0], q[1], q[2], q[3]);
    }
    {
      const float* wp = Wc + (size_t)(s0 + srow8 * 8) * EMB + e0 + e4 * 4;
      f32x4 wvv[8];
#pragma unroll
      for (int r = 0; r < 8; ++r)
        wvv[r] = *reinterpret_cast<const f32x4*>(wp + (size_t)r * EMB);
#pragma unroll
      for (int i = 0; i < 4; ++i) {
        const int e_local = e4 * 4 + i;
        unsigned int q0 = f2bf(wvv[0][i]) | (f2bf(wvv[1][i]) << 16);
        unsigned int q1 = f2bf(wvv[2][i]) | (f2bf(wvv[3][i]) << 16);
        unsigned int q2 = f2bf(wvv[4][i]) | (f2bf(wvv[5][i]) << 16);
        unsigned int q3 = f2bf(wvv[6][i]) | (f2bf(wvv[7][i]) << 16);
        int byte = (e_local * 128 + srow8 * 16) ^ ((e_local & 7) << 4);
        *reinterpret_cast<uint4*>((char*)&Blds[0] + byte) =
            make_uint4(q0, q1, q2, q3);
      }
    }
    __syncthreads();
#pragma unroll
    for (int ks = 0; ks < 2; ++ks) {
      bf16x8 af[4], bfr[4];
#pragma unroll
      for (int mi = 0; mi < 4; ++mi) {
        int m_local = wr * 64 + mi * 16 + lm;
        int byte = (m_local * 128 + (ks * 4 + g) * 16) ^ ((m_local & 7) << 4);
        af[mi] = *reinterpret_cast<const bf16x8*>((const char*)&Alds[0] + byte);
      }
#pragma unroll
      for (int ni = 0; ni < 4; ++ni) {
        int e_local = wc * 64 + ni * 16 + lm;
        int byte = (e_local * 128 + (ks * 4 + g) * 16) ^ ((e_local & 7) << 4);
        bfr[ni] = *reinterpret_cast<const bf16x8*>((const char*)&Blds[0] + byte);
      }
#pragma unroll
      for (int mi = 0; mi < 4; ++mi)
#pragma unroll
        for (int ni = 0; ni < 4; ++ni)
          acc[mi][ni] = __builtin_amdgcn_mfma_f32_16x16x32_bf16(
              af[mi], bfr[ni], acc[mi][ni], 0, 0, 0);
    }
    __syncthreads();
  }
  const float* bc = bias + (size_t)c * EMB;
#pragma unroll
  for (int ni = 0; ni < 4; ++ni) {
    const int e = e0 + wc * 64 + ni * 16 + lm;
    const float bv = bc[e];
#pragma unroll
    for (int mi = 0; mi < 4; ++mi) {
      f32x4 a = acc[mi][ni];
      const int mbase = b0 + wr * 64 + mi * 16 + g * 4;
#pragma unroll
      for (int r = 0; r < 4; ++r) {
        float v = a[r] + bv;
        v = fmaxf(v, 0.f);
        out[((size_t)(mbase + r) * NC + c) * EMB + e] = v;
      }
    }
  }
}

extern "C" void kernel_launch(void* const* d_in, const int* in_sizes, int n_in,
                              void* d_out, int out_size, void* d_ws, size_t ws_size,
                              hipStream_t stream) {
  const float* x    = (const float*)d_in[0];
  const float* W    = (const float*)d_in[1];
  const float* bias = (const float*)d_in[2];
  float* out        = (float*)d_out;

  const size_t xT_bytes = (size_t)NC * BATCH * SEQ * sizeof(ushort_t);

  if (ws_size >= xT_bytes) {
    ushort_t* xT = (ushort_t*)d_ws;
    transpose_x_kernel<<<BATCH * (SEQ / 64), 256, 0, stream>>>(x, xT);
    grouped_gemm_pipe<<<NC * (EMB / 256), 1024, 0, stream>>>(xT, W, bias, out);
  } else {
    grouped_gemm_fallback<<<NC * 2 * (EMB / 128), 256, 0, stream>>>(x, W, bias, out);
  }
}

// Round 16
// 148.620 us; speedup vs baseline: 2.8464x; 2.8464x over previous
//
#include <hip/hip_runtime.h>

#define BATCH 256
#define SEQ   2048
#define NC    32
#define EMB   2048
#define NT    32          // SEQ / BK, BK = 64

typedef unsigned short ushort_t;
using f32x4  = __attribute__((ext_vector_type(4))) float;
using bf16x8 = __attribute__((ext_vector_type(8))) short;

using u32_gl = __attribute__((address_space(1))) const unsigned int;
using u32_ld = __attribute__((address_space(3))) unsigned int;

__device__ __forceinline__ unsigned int f2bf(float f) {
  unsigned int u = __float_as_uint(f);
  u += 0x7FFFu + ((u >> 16) & 1u);   // RNE (finite inputs)
  return u >> 16;
}

#define SB() __builtin_amdgcn_sched_barrier(0)

// ---------------------------------------------------------------------------
// x: (B, S, C) f32  ->  xT: (C, B, S) bf16
// ---------------------------------------------------------------------------
__global__ __launch_bounds__(256) void transpose_x_kernel(
    const float* __restrict__ x, ushort_t* __restrict__ xT) {
  __shared__ float tile[64][33];
  const int b  = blockIdx.x >> 5;
  const int st = blockIdx.x & 31;
  const int t  = threadIdx.x;
  const float* src = x + ((size_t)b * SEQ + (size_t)st * 64) * NC;
#pragma unroll
  for (int i = 0; i < 2; ++i) {
    int idx = t + i * 256;
    float4 v = reinterpret_cast<const float4*>(src)[idx];
    int s = idx >> 3;
    int c = (idx & 7) * 4;
    tile[s][c + 0] = v.x; tile[s][c + 1] = v.y;
    tile[s][c + 2] = v.z; tile[s][c + 3] = v.w;
  }
  __syncthreads();
  const int c  = t >> 3;
  const int si = (t & 7) * 8;
  unsigned int q[4];
#pragma unroll
  for (int p = 0; p < 4; ++p) {
    unsigned int h0 = f2bf(tile[si + 2 * p + 0][c]);
    unsigned int h1 = f2bf(tile[si + 2 * p + 1][c]);
    q[p] = h0 | (h1 << 16);
  }
  ushort_t* dst = xT + (size_t)c * (BATCH * SEQ) + (size_t)b * SEQ + st * 64 + si;
  *reinterpret_cast<uint4*>(dst) = make_uint4(q[0], q[1], q[2], q[3]);
}

// ---------------------------------------------------------------------------
// CHAMPION (R10/R14, 148.1-149.2 us): BM=256 / BN=128 / BK=64, 512 thr =
// 8 waves as 4m x 2e, A dbuf 64 KB + B dbuf 32 KB = 96 KB, counted vmcnt,
// conflict-free B writes (scalar-e W ownership: write lanes cover 32
// consecutive e), NT load/store hints, ONE barrier per iter:
//   a. issue W(t+1):16         b. vmcnt(20) -> W(t) ready
//   c. convert/write B(t)      d. vmcnt(16) -> A(t) landed (own gl_lds)
//   e. lgkmcnt(0) + s_barrier  f. issue gl_lds A(t+1) (WAR-safe post-barrier)
//   g. compute(t)
// Queue entering iter t: [W(t):16, A(t):4] = 20 (max in-flight 36 < 63).
// ---------------------------------------------------------------------------
template <int P>
__device__ __forceinline__ void gemm_iter(
    int t, const ushort_t* __restrict__ xTc, const float* __restrict__ Wc,
    char* Alds, char* Blds, float (&wvs)[2][16], f32x4 (&acc)[4][4],
    int tid, int wr, int wc, int g, int lm, int e0) {
  const int srow4 = tid >> 5;        // 0..15 -> W s-rows srow4*4..+3
  const int e4    = tid & 31;        // 0..31 -> base e column

  // ---- a. issue W(t+1): 16 NT scalar loads ----
  {
    const int tn = (t + 1) & (NT - 1);
    const float* wp = Wc + (size_t)(tn * 64 + srow4 * 4) * EMB + e0 + e4;
#pragma unroll
    for (int r = 0; r < 4; ++r)
#pragma unroll
      for (int i = 0; i < 4; ++i)
        wvs[P ^ 1][r * 4 + i] =
            __builtin_nontemporal_load(wp + (size_t)r * EMB + 32 * i);
  }
  SB();

  // ---- b. W(t) ready; leave [A(t):4, W(t+1):16] in flight ----
  asm volatile("s_waitcnt vmcnt(20)" ::: "memory");

  // ---- c. convert W(t) -> Blds[P] (lanes = 32 consecutive e: free) ----
#pragma unroll
  for (int i = 0; i < 4; ++i) {
    const int e_local = e4 + 32 * i;
    unsigned int lo = f2bf(wvs[P][0 * 4 + i]) | (f2bf(wvs[P][1 * 4 + i]) << 16);
    unsigned int hi = f2bf(wvs[P][2 * 4 + i]) | (f2bf(wvs[P][3 * 4 + i]) << 16);
    int byte = (e_local * 128 + srow4 * 8) ^ ((e_local & 7) << 4);
    *reinterpret_cast<uint2*>(Blds + P * 16384 + byte) = make_uint2(lo, hi);
  }
  SB();

  // ---- d. own A(t) gl_lds landed; leave [W(t+1):16] ----
  asm volatile("s_waitcnt vmcnt(16)" ::: "memory");

  // ---- e. single barrier (B writes + A arrival both sealed) ----
  asm volatile("s_waitcnt lgkmcnt(0)" ::: "memory");
  __builtin_amdgcn_s_barrier();

  // ---- f. stage A(t+1) early (hides HBM latency under compute) ----
  {
    const int s0n = ((t + 1) & (NT - 1)) * 64;
#pragma unroll
    for (int i = 0; i < 4; ++i) {
      int ch   = i * 512 + tid;
      int m    = ch >> 3;
      int slot = (ch & 7) ^ (m & 7);
      const ushort_t* src = xTc + (size_t)m * SEQ + s0n + slot * 8;
      __builtin_amdgcn_global_load_lds(
          (u32_gl*)src, (u32_ld*)(Alds + (P ^ 1) * 32768 + ch * 16), 16, 0, 0);
    }
  }
  SB();

  // ---- g. compute(t) from parity-P buffers ----
#pragma unroll
  for (int ks = 0; ks < 2; ++ks) {
    bf16x8 af[4], bfr[4];
#pragma unroll
    for (int mi = 0; mi < 4; ++mi) {
      int m_local = wr * 64 + mi * 16 + lm;
      int byte = (m_local * 128 + (ks * 4 + g) * 16) ^ ((m_local & 7) << 4);
      af[mi] = *reinterpret_cast<const bf16x8*>(Alds + P * 32768 + byte);
    }
#pragma unroll
    for (int ni = 0; ni < 4; ++ni) {
      int e_local = wc * 64 + ni * 16 + lm;
      int byte = (e_local * 128 + (ks * 4 + g) * 16) ^ ((e_local & 7) << 4);
      bfr[ni] = *reinterpret_cast<const bf16x8*>(Blds + P * 16384 + byte);
    }
#pragma unroll
    for (int mi = 0; mi < 4; ++mi)
#pragma unroll
      for (int ni = 0; ni < 4; ++ni)
        acc[mi][ni] = __builtin_amdgcn_mfma_f32_16x16x32_bf16(
            af[mi], bfr[ni], acc[mi][ni], 0, 0, 0);
  }
}

__global__ __launch_bounds__(512, 2) void grouped_gemm_pipe(
    const ushort_t* __restrict__ xT,  // (C,B,S) bf16
    const float* __restrict__ W,      // (C,S,E) f32
    const float* __restrict__ bias,   // (C,E) f32
    float* __restrict__ out) {        // (B,C,E) f32
  __shared__ ushort_t AldsU[2][256 * 64];  // 64 KB
  __shared__ ushort_t BldsU[2][128 * 64];  // 32 KB -> 96 KB total

  // Bijective XCD-chunked swizzle: nwg = 512, 64 per XCD
  // (all 16 e-tiles of a channel on one XCD -> A slice L2-shared).
  const int bid = (blockIdx.x & 7) * 64 + (blockIdx.x >> 3);
  const int c   = bid >> 4;
  const int et  = bid & 15;
  const int e0  = et * 128;

  const int tid  = threadIdx.x;
  const int w    = tid >> 6;
  const int wr   = w >> 1;           // 0..3 m-quadrant
  const int wc   = w & 1;            // 0..1 e-half
  const int lane = tid & 63;
  const int g    = lane >> 4;
  const int lm   = lane & 15;

  const float* Wc = W + (size_t)c * SEQ * EMB;
  const ushort_t* xTc = xT + (size_t)c * (BATCH * SEQ);
  char* Alds = (char*)&AldsU[0][0];
  char* Blds = (char*)&BldsU[0][0];

  float wvs[2][16];
  f32x4 acc[4][4];
#pragma unroll
  for (int i = 0; i < 4; ++i)
#pragma unroll
    for (int j = 0; j < 4; ++j) acc[i][j] = (f32x4){0.f, 0.f, 0.f, 0.f};

  // ---- prologue: issue W(0):16, then gl_lds A(0):4 -> queue = 20 ----
  {
    const int srow4 = tid >> 5;
    const int e4    = tid & 31;
    const float* wp = Wc + (size_t)(srow4 * 4) * EMB + e0 + e4;
#pragma unroll
    for (int r = 0; r < 4; ++r)
#pragma unroll
      for (int i = 0; i < 4; ++i)
        wvs[0][r * 4 + i] =
            __builtin_nontemporal_load(wp + (size_t)r * EMB + 32 * i);
    SB();
#pragma unroll
    for (int i = 0; i < 4; ++i) {
      int ch   = i * 512 + tid;
      int m    = ch >> 3;
      int slot = (ch & 7) ^ (m & 7);
      const ushort_t* src = xTc + (size_t)m * SEQ + slot * 8;
      __builtin_amdgcn_global_load_lds(
          (u32_gl*)src, (u32_ld*)(Alds + ch * 16), 16, 0, 0);
    }
    SB();
  }

  // ---- main loop, unroll-by-2 for compile-time parity ----
  for (int t = 0; t < NT; t += 2) {
    gemm_iter<0>(t,     xTc, Wc, Alds, Blds, wvs, acc, tid, wr, wc, g, lm, e0);
    gemm_iter<1>(t + 1, xTc, Wc, Alds, Blds, wvs, acc, tid, wr, wc, g, lm, e0);
  }

  // drain wrapped prefetch before epilogue
  asm volatile("s_waitcnt vmcnt(0)" ::: "memory");

  // ---- epilogue: bias + ReLU; NT stores (out is write-once) ----
  const float* bc = bias + (size_t)c * EMB;
#pragma unroll
  for (int ni = 0; ni < 4; ++ni) {
    const int e = e0 + wc * 64 + ni * 16 + lm;
    const float bv = bc[e];
#pragma unroll
    for (int mi = 0; mi < 4; ++mi) {
      f32x4 a = acc[mi][ni];
      const int mbase = wr * 64 + mi * 16 + g * 4;
#pragma unroll
      for (int r = 0; r < 4; ++r) {
        float v = a[r] + bv;
        v = fmaxf(v, 0.f);
        __builtin_nontemporal_store(
            v, out + ((size_t)(mbase + r) * NC + c) * EMB + e);
      }
    }
  }
}

// ---------------------------------------------------------------------------
// Fallback (no workspace): round-1 style, A loaded strided from x directly.
// ---------------------------------------------------------------------------
__global__ __launch_bounds__(256, 2) void grouped_gemm_fallback(
    const float* __restrict__ x, const float* __restrict__ W,
    const float* __restrict__ bias, float* __restrict__ out) {
  __shared__ ushort_t Alds[128 * 64];
  __shared__ ushort_t Blds[128 * 64];
  const int bid = blockIdx.x;
  const int c   = bid >> 5;
  const int et  = (bid >> 1) & 15;
  const int bt  = bid & 1;
  const int b0  = bt * 128;
  const int e0  = et * 128;
  const int tid  = threadIdx.x;
  const int w    = tid >> 6;
  const int wr   = w >> 1;
  const int wc   = w & 1;
  const int lane = tid & 63;
  const int g    = lane >> 4;
  const int lm   = lane & 15;
  const float* Wc = W + (size_t)c * SEQ * EMB;
  const int srow8 = tid >> 5;
  const int e4    = tid & 31;
  f32x4 acc[4][4];
#pragma unroll
  for (int i = 0; i < 4; ++i)
#pragma unroll
    for (int j = 0; j < 4; ++j) acc[i][j] = (f32x4){0.f, 0.f, 0.f, 0.f};
  for (int s0 = 0; s0 < SEQ; s0 += 64) {
#pragma unroll
    for (int i = 0; i < 4; ++i) {
      int ch   = i * 256 + tid;
      int m    = ch >> 3;
      int slot = (ch & 7) ^ (m & 7);
      const float* src = x + (size_t)(b0 + m) * (SEQ * NC)
                           + (size_t)(s0 + slot * 8) * NC + c;
      unsigned int q[4];
#pragma unroll
      for (int p = 0; p < 4; ++p) {
        unsigned int h0 = f2bf(src[(2 * p + 0) * NC]);
        unsigned int h1 = f2bf(src[(2 * p + 1) * NC]);
        q[p] = h0 | (h1 << 16);
      }
      *reinterpret_cast<uint4*>((char*)&Alds[0] + ch * 16) =
          make_uint4(q[0], q[1], q[2], q[3]);
    }
    {
      const float* wp = Wc + (size_t)(s0 + srow8 * 8) * EMB + e0 + e4 * 4;
      f32x4 wvv[8];
#pragma unroll
      for (int r = 0; r < 8; ++r)
        wvv[r] = *reinterpret_cast<const f32x4*>(wp + (size_t)r * EMB);
#pragma unroll
      for (int i = 0; i < 4; ++i) {
        const int e_local = e4 * 4 + i;
        unsigned int q0 = f2bf(wvv[0][i]) | (f2bf(wvv[1][i]) << 16);
        unsigned int q1 = f2bf(wvv[2][i]) | (f2bf(wvv[3][i]) << 16);
        unsigned int q2 = f2bf(wvv[4][i]) | (f2bf(wvv[5][i]) << 16);
        unsigned int q3 = f2bf(wvv[6][i]) | (f2bf(wvv[7][i]) << 16);
        int byte = (e_local * 128 + srow8 * 16) ^ ((e_local & 7) << 4);
        *reinterpret_cast<uint4*>((char*)&Blds[0] + byte) =
            make_uint4(q0, q1, q2, q3);
      }
    }
    __syncthreads();
#pragma unroll
    for (int ks = 0; ks < 2; ++ks) {
      bf16x8 af[4], bfr[4];
#pragma unroll
      for (int mi = 0; mi < 4; ++mi) {
        int m_local = wr * 64 + mi * 16 + lm;
        int byte = (m_local * 128 + (ks * 4 + g) * 16) ^ ((m_local & 7) << 4);
        af[mi] = *reinterpret_cast<const bf16x8*>((const char*)&Alds[0] + byte);
      }
#pragma unroll
      for (int ni = 0; ni < 4; ++ni) {
        int e_local = wc * 64 + ni * 16 + lm;
        int byte = (e_local * 128 + (ks * 4 + g) * 16) ^ ((e_local & 7) << 4);
        bfr[ni] = *reinterpret_cast<const bf16x8*>((const char*)&Blds[0] + byte);
      }
#pragma unroll
      for (int mi = 0; mi < 4; ++mi)
#pragma unroll
        for (int ni = 0; ni < 4; ++ni)
          acc[mi][ni] = __builtin_amdgcn_mfma_f32_16x16x32_bf16(
              af[mi], bfr[ni], acc[mi][ni], 0, 0, 0);
    }
    __syncthreads();
  }
  const float* bc = bias + (size_t)c * EMB;
#pragma unroll
  for (int ni = 0; ni < 4; ++ni) {
    const int e = e0 + wc * 64 + ni * 16 + lm;
    const float bv = bc[e];
#pragma unroll
    for (int mi = 0; mi < 4; ++mi) {
      f32x4 a = acc[mi][ni];
      const int mbase = b0 + wr * 64 + mi * 16 + g * 4;
#pragma unroll
      for (int r = 0; r < 4; ++r) {
        float v = a[r] + bv;
        v = fmaxf(v, 0.f);
        out[((size_t)(mbase + r) * NC + c) * EMB + e] = v;
      }
    }
  }
}

extern "C" void kernel_launch(void* const* d_in, const int* in_sizes, int n_in,
                              void* d_out, int out_size, void* d_ws, size_t ws_size,
                              hipStream_t stream) {
  const float* x    = (const float*)d_in[0];
  const float* W    = (const float*)d_in[1];
  const float* bias = (const float*)d_in[2];
  float* out        = (float*)d_out;

  const size_t xT_bytes = (size_t)NC * BATCH * SEQ * sizeof(ushort_t);

  if (ws_size >= xT_bytes) {
    ushort_t* xT = (ushort_t*)d_ws;
    transpose_x_kernel<<<BATCH * (SEQ / 64), 256, 0, stream>>>(x, xT);
    grouped_gemm_pipe<<<NC * (EMB / 128), 512, 0, stream>>>(xT, W, bias, out);
  } else {
    grouped_gemm_fallback<<<NC * 2 * (EMB / 128), 256, 0, stream>>>(x, W, bias, out);
  }
}